// Round 4
// baseline (278.818 us; speedup 1.0000x reference)
//
#include <hip/hip_runtime.h>
#include <math.h>

#define H 2048
#define E 64
#define MROWS 16      // rows per block
#define KC 256        // k per chunk
#define NCHUNK 8
#define LROW 264      // LDS row stride in f16 (256 + 8 pad -> staggers banks)

typedef _Float16 half8  __attribute__((ext_vector_type(8)));
typedef _Float16 half4h __attribute__((ext_vector_type(4)));
typedef float    f32x4  __attribute__((ext_vector_type(4)));

#define MFMA16(A,B,C) __builtin_amdgcn_mfma_f32_16x16x32_f16(A,B,C,0,0,0)

// ws layout: Bh[H*E f16] | Bl[H*E f16] | csum[E f32] | bsum[E f32]  (=512.5 KB)

// Pack W' = lnw*W into MFMA B-fragment layout, f16 hi/lo split (lo scaled by 2048).
// Fragment (ks, et): lane l holds B[k = ks*32 + (l>>4)*8 + j][n = et*16 + (l&15)], j=0..7.
__global__ __launch_bounds__(256) void prep_pack(const float* __restrict__ W,
        const float* __restrict__ lnw, _Float16* __restrict__ Bh,
        _Float16* __restrict__ Bl) {
    int idx  = blockIdx.x * 256 + threadIdx.x;      // 0..16383
    int lane = idx & 63;
    int et   = (idx >> 6) & 3;
    int ks   = idx >> 8;                            // 0..63
    int e  = et * 16 + (lane & 15);
    int k0 = ks * 32 + ((lane >> 4) << 3);
    half8 hh, ll;
    #pragma unroll
    for (int j = 0; j < 8; ++j) {
        float wf = lnw[k0 + j] * W[e * H + k0 + j];
        _Float16 h = (_Float16)wf;
        _Float16 l = (_Float16)((wf - (float)h) * 2048.0f);
        hh[j] = h; ll[j] = l;
    }
    *(half8*)&Bh[(long)idx * 8] = hh;
    *(half8*)&Bl[(long)idx * 8] = ll;
}

__global__ __launch_bounds__(256) void prep_sums(const float* __restrict__ W,
        const float* __restrict__ lnw, const float* __restrict__ lnb,
        float* __restrict__ csum, float* __restrict__ bsum) {
    __shared__ float rc[256], rb[256];
    int e = blockIdx.x, t = threadIdx.x;
    float cs = 0.f, bs = 0.f;
    #pragma unroll
    for (int j = 0; j < 8; ++j) {
        int k = t + j * 256;
        float w = W[e * H + k];
        cs += lnw[k] * w;
        bs += lnb[k] * w;
    }
    rc[t] = cs; rb[t] = bs;
    __syncthreads();
    for (int s = 128; s > 0; s >>= 1) {
        if (t < s) { rc[t] += rc[t + s]; rb[t] += rb[t + s]; }
        __syncthreads();
    }
    if (t == 0) { csum[e] = rc[0]; bsum[e] = rb[0]; }
}

__global__ __launch_bounds__(256, 4) void router_kernel(
    const float* __restrict__ X, const _Float16* __restrict__ Bh,
    const _Float16* __restrict__ Bl, const float* __restrict__ csum,
    const float* __restrict__ bsum, float* __restrict__ out, int nRows)
{
    __shared__ __align__(16) _Float16 XhL[2][MROWS][LROW];   // 16,896 B
    __shared__ __align__(16) _Float16 XlL[2][MROWS][LROW];   // 16,896 B
    __shared__ float C2[MROWS][E + 4];                       // 4,352 B (pad 4)
    __shared__ float mu_s[MROWS], rs_s[MROWS];

    const int t    = threadIdx.x;
    const int lane = t & 63;
    const int wv   = t >> 6;                 // wave 0..3 -> e-tile wv (experts wv*16..+16)
    const int q    = lane >> 4;              // quad 0..3
    const int ln16 = lane & 15;
    const long rowBase = (long)blockIdx.x * MROWS;
    const long iOff = (long)nRows * 2;
    const long lOff = (long)nRows * 4;

    const float4* X4 = (const float4*)X;
    const int c4 = t & 63;                   // float4 col within chunk row

    // per-thread stats slots: row = wv + 4*jj
    float sA[4] = {0.f, 0.f, 0.f, 0.f};
    float qA[4] = {0.f, 0.f, 0.f, 0.f};

    f32x4 a0[4], a1[4], a2[4];
    #pragma unroll
    for (int i = 0; i < 4; ++i) { a0[i] = (f32x4)0.f; a1[i] = (f32x4)0.f; a2[i] = (f32x4)0.f; }
    // NOTE: accumulate a1/a2 per ks into per-iteration regs? -> keep single set:
    // a0..a2 indexed [reg] after MFMA (4 f32 each); we use only index [0..3] of f32x4.
    // (f32x4 = 4 regs = the 16x16 C fragment.)
    f32x4 acc0 = (f32x4)0.f, acc1 = (f32x4)0.f, acc2 = (f32x4)0.f;

    // preload chunk 0 (4 float4 per thread)
    float4 vbuf[4];
    #pragma unroll
    for (int jj = 0; jj < 4; ++jj) {
        int r = wv + jj * 4;
        vbuf[jj] = X4[(rowBase + r) * 512 + c4];
    }

    for (int ch = 0; ch < NCHUNK; ++ch) {
        const int buf = ch & 1;
        // ---- convert + stats + LDS write ----
        #pragma unroll
        for (int jj = 0; jj < 4; ++jj) {
            float4 v = vbuf[jj];
            int r = wv + jj * 4;
            sA[jj] += v.x + v.y + v.z + v.w;
            qA[jj] += v.x * v.x + v.y * v.y + v.z * v.z + v.w * v.w;
            _Float16 h0 = (_Float16)v.x, h1 = (_Float16)v.y,
                     h2 = (_Float16)v.z, h3 = (_Float16)v.w;
            _Float16 l0 = (_Float16)((v.x - (float)h0) * 2048.f);
            _Float16 l1 = (_Float16)((v.y - (float)h1) * 2048.f);
            _Float16 l2 = (_Float16)((v.z - (float)h2) * 2048.f);
            _Float16 l3 = (_Float16)((v.w - (float)h3) * 2048.f);
            half4h hh = {h0, h1, h2, h3};
            half4h ll = {l0, l1, l2, l3};
            *(half4h*)&XhL[buf][r][c4 * 4] = hh;
            *(half4h*)&XlL[buf][r][c4 * 4] = ll;
        }
        __syncthreads();

        // ---- issue next chunk's global loads (in flight across MFMA phase) ----
        if (ch + 1 < NCHUNK) {
            #pragma unroll
            for (int jj = 0; jj < 4; ++jj) {
                int r = wv + jj * 4;
                vbuf[jj] = X4[(rowBase + r) * 512 + (ch + 1) * 64 + c4];
            }
        }

        // ---- MFMA sweep over this chunk ----
        #pragma unroll
        for (int ksl = 0; ksl < 8; ++ksl) {
            int ks = ch * 8 + ksl;
            half8 Ah = *(const half8*)&XhL[buf][ln16][ksl * 32 + q * 8];
            half8 Al = *(const half8*)&XlL[buf][ln16][ksl * 32 + q * 8];
            long bo = ((long)(ks * 4 + wv) * 64 + lane) * 8;
            half8 Wh = *(const half8*)&Bh[bo];
            half8 Wl = *(const half8*)&Bl[bo];
            acc0 = MFMA16(Ah, Wh, acc0);
            acc1 = MFMA16(Ah, Wl, acc1);
            acc2 = MFMA16(Al, Wl, acc2);
            acc1 = MFMA16(Al, Wh, acc1);
        }
        __syncthreads();
    }

    // ---- finalize LN stats ----
    #pragma unroll
    for (int jj = 0; jj < 4; ++jj) {
        float s = sA[jj], q2 = qA[jj];
        #pragma unroll
        for (int d = 1; d < 64; d <<= 1) {
            s  += __shfl_xor(s, d);
            q2 += __shfl_xor(q2, d);
        }
        if (lane == 0) {
            int r = wv + jj * 4;
            float mu  = s * (1.f / H);
            float var = q2 * (1.f / H) - mu * mu;
            mu_s[r] = mu;
            rs_s[r] = rsqrtf(var + 1e-5f);
        }
    }
    __syncthreads();

    // ---- epilogue: combine splits, LN rank-1 correction, clip, write logits ----
    {
        int n = wv * 16 + ln16;
        float cs = csum[n], bs = bsum[n];
        #pragma unroll
        for (int reg = 0; reg < 4; ++reg) {
            int m = q * 4 + reg;
            float raw = acc0[reg] + acc1[reg] * (1.f / 2048.f)
                                  + acc2[reg] * (1.f / 4194304.f);
            float lg = rs_s[m] * (raw - mu_s[m] * cs) + bs;
            lg = fminf(fmaxf(lg, -10.f), 10.f);
            out[lOff + (rowBase + m) * 64 + n] = lg;
            C2[m][n] = lg;
        }
    }
    __syncthreads();

    // ---- softmax + top2: wave wv handles rows wv*4 .. wv*4+3 ----
    #pragma unroll
    for (int rr = 0; rr < 4; ++rr) {
        int r = wv * 4 + rr;
        float l = C2[r][lane];
        float m = l;
        #pragma unroll
        for (int d = 1; d < 64; d <<= 1) m = fmaxf(m, __shfl_xor(m, d));
        float p = __expf(l - m);
        float ssum = p;
        #pragma unroll
        for (int d = 1; d < 64; d <<= 1) ssum += __shfl_xor(ssum, d);
        float prob = fminf(fmaxf(p / ssum, 1e-4f), 1.0f);

        float v1 = prob; int i1 = lane;
        #pragma unroll
        for (int d = 1; d < 64; d <<= 1) {
            float ov = __shfl_xor(v1, d);
            int   oi = __shfl_xor(i1, d);
            if (ov > v1 || (ov == v1 && oi < i1)) { v1 = ov; i1 = oi; }
        }
        float v2 = (lane == i1) ? -1.f : prob; int i2 = lane;
        #pragma unroll
        for (int d = 1; d < 64; d <<= 1) {
            float ov = __shfl_xor(v2, d);
            int   oi = __shfl_xor(i2, d);
            if (ov > v2 || (ov == v2 && oi < i2)) { v2 = ov; i2 = oi; }
        }
        if (lane == 0) {
            float ps = fmaxf(v1 + v2, 1e-4f);
            long rg_ = rowBase + r;
            out[rg_ * 2 + 0] = v1 / ps;
            out[rg_ * 2 + 1] = v2 / ps;
            out[iOff + rg_ * 2 + 0] = (float)i1;
            out[iOff + rg_ * 2 + 1] = (float)i2;
        }
    }
}

extern "C" void kernel_launch(void* const* d_in, const int* in_sizes, int n_in,
                              void* d_out, int out_size, void* d_ws, size_t ws_size,
                              hipStream_t stream) {
    const float* X   = (const float*)d_in[0];
    const float* lnw = (const float*)d_in[1];
    const float* lnb = (const float*)d_in[2];
    const float* W   = (const float*)d_in[3];
    float* outp = (float*)d_out;

    _Float16* Bh = (_Float16*)d_ws;
    _Float16* Bl = Bh + H * E;
    float* csum  = (float*)(Bl + H * E);
    float* bsum  = csum + E;

    int N = in_sizes[0] / H;                 // 16384 rows

    prep_pack<<<(H * E / 8) / 256, 256, 0, stream>>>(W, lnw, Bh, Bl);
    prep_sums<<<E, 256, 0, stream>>>(W, lnw, lnb, csum, bsum);
    router_kernel<<<N / MROWS, 256, 0, stream>>>(X, Bh, Bl, csum, bsum, outp, N);
}

// Round 5
// 269.466 us; speedup vs baseline: 1.0347x; 1.0347x over previous
//
#include <hip/hip_runtime.h>
#include <math.h>

#define H 2048
#define E 64
#define MROWS 16      // rows per block
#define NCHUNK 8      // 8 chunks of 256 k
#define LROW 264      // LDS row stride in f16 (256 + 8 pad; 528 B = 16B-aligned rows)

typedef _Float16 half8  __attribute__((ext_vector_type(8)));
typedef _Float16 half4h __attribute__((ext_vector_type(4)));
typedef float    f32x4  __attribute__((ext_vector_type(4)));

#define MFMA16(A,B,C) __builtin_amdgcn_mfma_f32_16x16x32_f16(A,B,C,0,0,0)

// ws layout: Bh[H*E f16] | Bl[H*E f16] | csum[E f32] | bsum[E f32]

// Pack W' = lnw*W into MFMA B-fragment layout, f16 hi/lo split (lo scaled by 2048).
// Fragment (ks, et): lane l holds B[k = ks*32 + (l>>4)*8 + j][n = et*16 + (l&15)], j=0..7.
__global__ __launch_bounds__(256) void prep_pack(const float* __restrict__ W,
        const float* __restrict__ lnw, _Float16* __restrict__ Bh,
        _Float16* __restrict__ Bl) {
    int idx  = blockIdx.x * 256 + threadIdx.x;      // 0..16383
    int lane = idx & 63;
    int ks   = idx >> 8;                            // 0..63
    int e  = ((idx >> 6) & 3) * 16 + (lane & 15);
    int k0 = ks * 32 + ((lane >> 4) << 3);
    half8 hh, ll;
    #pragma unroll
    for (int j = 0; j < 8; ++j) {
        float wf = lnw[k0 + j] * W[e * H + k0 + j];
        _Float16 h = (_Float16)wf;
        _Float16 l = (_Float16)((wf - (float)h) * 2048.0f);
        hh[j] = h; ll[j] = l;
    }
    *(half8*)&Bh[(long)idx * 8] = hh;
    *(half8*)&Bl[(long)idx * 8] = ll;
}

__global__ __launch_bounds__(256) void prep_sums(const float* __restrict__ W,
        const float* __restrict__ lnw, const float* __restrict__ lnb,
        float* __restrict__ csum, float* __restrict__ bsum) {
    __shared__ float rc[256], rb[256];
    int e = blockIdx.x, t = threadIdx.x;
    float cs = 0.f, bs = 0.f;
    #pragma unroll
    for (int j = 0; j < 8; ++j) {
        int k = t + j * 256;
        float w = W[e * H + k];
        cs += lnw[k] * w;
        bs += lnb[k] * w;
    }
    rc[t] = cs; rb[t] = bs;
    __syncthreads();
    for (int s = 128; s > 0; s >>= 1) {
        if (t < s) { rc[t] += rc[t + s]; rb[t] += rb[t + s]; }
        __syncthreads();
    }
    if (t == 0) { csum[e] = rc[0]; bsum[e] = rb[0]; }
}

__global__ __launch_bounds__(256) void router_kernel(
    const float* __restrict__ X, const _Float16* __restrict__ Bh,
    const _Float16* __restrict__ Bl, const float* __restrict__ csum,
    const float* __restrict__ bsum, float* __restrict__ out, int nRows)
{
    __shared__ __align__(16) _Float16 XhL[2][MROWS][LROW];   // 16,896 B
    __shared__ __align__(16) _Float16 XlL[2][MROWS][LROW];   // 16,896 B
    __shared__ float C2[MROWS][E + 4];                       // 4,352 B
    __shared__ float mu_s[MROWS], rs_s[MROWS];

    const int t    = threadIdx.x;
    const int lane = t & 63;
    const int wv   = t >> 6;                 // wave 0..3 -> expert tile wv*16..+16
    const int q    = lane >> 4;              // quad 0..3
    const int ln16 = lane & 15;
    const long rowBase = (long)blockIdx.x * MROWS;
    const long iOff = (long)nRows * 2;
    const long lOff = (long)nRows * 4;

    const float4* X4 = (const float4*)X;
    const int c4 = t & 63;                   // float4 col within chunk row

    float sA[4] = {0.f, 0.f, 0.f, 0.f};      // stats for row wv + 4*jj
    float qA[4] = {0.f, 0.f, 0.f, 0.f};

    f32x4 acc0 = (f32x4)0.f, acc1 = (f32x4)0.f, acc2 = (f32x4)0.f;

    // preload chunk 0 (4 float4 per thread)
    float4 vbuf[4];
    #pragma unroll
    for (int jj = 0; jj < 4; ++jj)
        vbuf[jj] = X4[(rowBase + wv + jj * 4) * 512 + c4];

    for (int ch = 0; ch < NCHUNK; ++ch) {
        const int buf = ch & 1;
        // ---- convert + stats + LDS write (consumes vbuf) ----
        #pragma unroll
        for (int jj = 0; jj < 4; ++jj) {
            float4 v = vbuf[jj];
            int r = wv + jj * 4;
            sA[jj] += v.x + v.y + v.z + v.w;
            qA[jj] += v.x * v.x + v.y * v.y + v.z * v.z + v.w * v.w;
            _Float16 h0 = (_Float16)v.x, h1 = (_Float16)v.y,
                     h2 = (_Float16)v.z, h3 = (_Float16)v.w;
            _Float16 l0 = (_Float16)((v.x - (float)h0) * 2048.f);
            _Float16 l1 = (_Float16)((v.y - (float)h1) * 2048.f);
            _Float16 l2 = (_Float16)((v.z - (float)h2) * 2048.f);
            _Float16 l3 = (_Float16)((v.w - (float)h3) * 2048.f);
            half4h hh = {h0, h1, h2, h3};
            half4h ll = {l0, l1, l2, l3};
            *(half4h*)&XhL[buf][r][c4 * 4] = hh;
            *(half4h*)&XlL[buf][r][c4 * 4] = ll;
        }

        // ---- issue next chunk's global loads before the barrier ----
        if (ch + 1 < NCHUNK) {
            #pragma unroll
            for (int jj = 0; jj < 4; ++jj)
                vbuf[jj] = X4[(rowBase + wv + jj * 4) * 512 + (ch + 1) * 64 + c4];
        }
        __syncthreads();   // single barrier per chunk; double-buffer covers WAR

        // ---- MFMA sweep over this chunk ----
        #pragma unroll
        for (int ksl = 0; ksl < 8; ++ksl) {
            int ks = ch * 8 + ksl;
            half8 Ah = *(const half8*)&XhL[buf][ln16][ksl * 32 + q * 8];
            half8 Al = *(const half8*)&XlL[buf][ln16][ksl * 32 + q * 8];
            long bo = ((long)(ks * 4 + wv) * 64 + lane) * 8;
            half8 Wh = *(const half8*)&Bh[bo];
            half8 Wl = *(const half8*)&Bl[bo];
            acc0 = MFMA16(Ah, Wh, acc0);
            acc1 = MFMA16(Ah, Wl, acc1);
            acc2 = MFMA16(Al, Wl, acc2);
            acc1 = MFMA16(Al, Wh, acc1);
        }
    }

    // ---- finalize LN stats ----
    #pragma unroll
    for (int jj = 0; jj < 4; ++jj) {
        float s = sA[jj], q2 = qA[jj];
        #pragma unroll
        for (int d = 1; d < 64; d <<= 1) {
            s  += __shfl_xor(s, d);
            q2 += __shfl_xor(q2, d);
        }
        if (lane == 0) {
            int r = wv + jj * 4;
            float mu  = s * (1.f / H);
            float var = q2 * (1.f / H) - mu * mu;
            mu_s[r] = mu;
            rs_s[r] = rsqrtf(var + 1e-5f);
        }
    }
    __syncthreads();

    // ---- epilogue: combine splits, LN rank-1 correction, clip, write logits ----
    {
        int n = wv * 16 + ln16;
        float cs = csum[n], bs = bsum[n];
        #pragma unroll
        for (int reg = 0; reg < 4; ++reg) {
            int m = q * 4 + reg;
            float raw = acc0[reg] + acc1[reg] * (1.f / 2048.f)
                                  + acc2[reg] * (1.f / 4194304.f);
            float lg = rs_s[m] * (raw - mu_s[m] * cs) + bs;
            lg = fminf(fmaxf(lg, -10.f), 10.f);
            out[lOff + (rowBase + m) * 64 + n] = lg;
            C2[m][n] = lg;
        }
    }
    __syncthreads();

    // ---- softmax + top2: wave wv handles rows wv*4 .. wv*4+3 ----
    #pragma unroll
    for (int rr = 0; rr < 4; ++rr) {
        int r = wv * 4 + rr;
        float l = C2[r][lane];
        float m = l;
        #pragma unroll
        for (int d = 1; d < 64; d <<= 1) m = fmaxf(m, __shfl_xor(m, d));
        float p = __expf(l - m);
        float ssum = p;
        #pragma unroll
        for (int d = 1; d < 64; d <<= 1) ssum += __shfl_xor(ssum, d);
        float prob = fminf(fmaxf(p / ssum, 1e-4f), 1.0f);

        float v1 = prob; int i1 = lane;
        #pragma unroll
        for (int d = 1; d < 64; d <<= 1) {
            float ov = __shfl_xor(v1, d);
            int   oi = __shfl_xor(i1, d);
            if (ov > v1 || (ov == v1 && oi < i1)) { v1 = ov; i1 = oi; }
        }
        float v2 = (lane == i1) ? -1.f : prob; int i2 = lane;
        #pragma unroll
        for (int d = 1; d < 64; d <<= 1) {
            float ov = __shfl_xor(v2, d);
            int   oi = __shfl_xor(i2, d);
            if (ov > v2 || (ov == v2 && oi < i2)) { v2 = ov; i2 = oi; }
        }
        if (lane == 0) {
            float ps = fmaxf(v1 + v2, 1e-4f);
            long rg_ = rowBase + r;
            out[rg_ * 2 + 0] = v1 / ps;
            out[rg_ * 2 + 1] = v2 / ps;
            out[iOff + rg_ * 2 + 0] = (float)i1;
            out[iOff + rg_ * 2 + 1] = (float)i2;
        }
    }
}

extern "C" void kernel_launch(void* const* d_in, const int* in_sizes, int n_in,
                              void* d_out, int out_size, void* d_ws, size_t ws_size,
                              hipStream_t stream) {
    const float* X   = (const float*)d_in[0];
    const float* lnw = (const float*)d_in[1];
    const float* lnb = (const float*)d_in[2];
    const float* W   = (const float*)d_in[3];
    float* outp = (float*)d_out;

    _Float16* Bh = (_Float16*)d_ws;
    _Float16* Bl = Bh + H * E;
    float* csum  = (float*)(Bl + H * E);
    float* bsum  = csum + E;

    int N = in_sizes[0] / H;                 // 16384 rows

    prep_pack<<<(H * E / 8) / 256, 256, 0, stream>>>(W, lnw, Bh, Bl);
    prep_sums<<<E, 256, 0, stream>>>(W, lnw, lnb, csum, bsum);
    router_kernel<<<N / MROWS, 256, 0, stream>>>(X, Bh, Bl, csum, bsum, outp, N);
}

// Round 6
// 241.174 us; speedup vs baseline: 1.1561x; 1.1173x over previous
//
#include <hip/hip_runtime.h>
#include <math.h>

#define H 2048
#define E 64
#define MROWS 16      // rows per tile
#define NBLK 256      // persistent grid
#define LR 2056       // LDS row stride in f16 (2048 + 8; 16B-aligned rows)

typedef _Float16 half8  __attribute__((ext_vector_type(8)));
typedef _Float16 half4h __attribute__((ext_vector_type(4)));
typedef float    f32x4  __attribute__((ext_vector_type(4)));

#define MFMA16(A,B,C) __builtin_amdgcn_mfma_f32_16x16x32_f16(A,B,C,0,0,0)

// ws layout: Bh[H*E f16] | Bl[H*E f16] | csum[E f32] | bsum[E f32]

// Pack W' = lnw*W into MFMA B-fragment layout, f16 hi/lo split (lo scaled by 2048).
// Fragment (ks, et): lane l holds B[k = ks*32 + (l>>4)*8 + j][n = et*16 + (l&15)], j=0..7.
__global__ __launch_bounds__(256) void prep_pack(const float* __restrict__ W,
        const float* __restrict__ lnw, _Float16* __restrict__ Bh,
        _Float16* __restrict__ Bl) {
    int idx  = blockIdx.x * 256 + threadIdx.x;      // 0..16383
    int lane = idx & 63;
    int ks   = idx >> 8;                            // 0..63
    int e  = ((idx >> 6) & 3) * 16 + (lane & 15);
    int k0 = ks * 32 + ((lane >> 4) << 3);
    half8 hh, ll;
    #pragma unroll
    for (int j = 0; j < 8; ++j) {
        float wf = lnw[k0 + j] * W[e * H + k0 + j];
        _Float16 h = (_Float16)wf;
        _Float16 l = (_Float16)((wf - (float)h) * 2048.0f);
        hh[j] = h; ll[j] = l;
    }
    *(half8*)&Bh[(long)idx * 8] = hh;
    *(half8*)&Bl[(long)idx * 8] = ll;
}

__global__ __launch_bounds__(256) void prep_sums(const float* __restrict__ W,
        const float* __restrict__ lnw, const float* __restrict__ lnb,
        float* __restrict__ csum, float* __restrict__ bsum) {
    __shared__ float rc[256], rb[256];
    int e = blockIdx.x, t = threadIdx.x;
    float cs = 0.f, bs = 0.f;
    #pragma unroll
    for (int j = 0; j < 8; ++j) {
        int k = t + j * 256;
        float w = W[e * H + k];
        cs += lnw[k] * w;
        bs += lnb[k] * w;
    }
    rc[t] = cs; rb[t] = bs;
    __syncthreads();
    for (int s = 128; s > 0; s >>= 1) {
        if (t < s) { rc[t] += rc[t + s]; rb[t] += rb[t + s]; }
        __syncthreads();
    }
    if (t == 0) { csum[e] = rc[0]; bsum[e] = rb[0]; }
}

__global__ __launch_bounds__(512) void router_kernel(
    const float* __restrict__ X, const _Float16* __restrict__ Bh,
    const _Float16* __restrict__ Bl, const float* __restrict__ csum,
    const float* __restrict__ bsum, float* __restrict__ out, int nRows)
{
    __shared__ __align__(16) _Float16 Xh[MROWS][LR];   // 65,792 B
    __shared__ __align__(16) _Float16 Xl[MROWS][LR];   // 65,792 B
    __shared__ float redC[4][64][4];                   //  4,096 B
    __shared__ float C2[MROWS][E + 4];                 //  4,352 B
    __shared__ float mu_s[MROWS], rs_s[MROWS];

    const int t    = threadIdx.x;
    const int lane = t & 63;
    const int wv   = t >> 6;                 // wave 0..7
    const int et   = wv & 3;                 // expert tile (16 experts)
    const int kh   = wv >> 2;                // K half (0/1)
    const int q    = lane >> 4;              // quad 0..3
    const int ln16 = lane & 15;
    const int rS   = t >> 5;                 // staging row 0..15 (32 thr/row)
    const int cS   = t & 31;                 // staging float4 lane within row
    const long iOff = (long)nRows * 2;
    const long lOff = (long)nRows * 4;

    const int tiles = nRows / (NBLK * MROWS);          // 4
    const float4* X4 = (const float4*)X;

    // prologue: issue tile 0's X loads (16 float4/thread, all in flight)
    float4 vbuf[16];
    {
        const float4* src = X4 + ((long)blockIdx.x * tiles * MROWS + rS) * 512;
        #pragma unroll
        for (int j = 0; j < 16; ++j) vbuf[j] = src[cS + j * 32];
    }

    for (int tile = 0; tile < tiles; ++tile) {
        const long rowBase = ((long)blockIdx.x * tiles + tile) * MROWS;

        // ---- convert + stats + LDS write (consumes vbuf) ----
        float s = 0.f, qq = 0.f;
        #pragma unroll
        for (int j = 0; j < 16; ++j) {
            float4 v = vbuf[j];
            s  += v.x + v.y + v.z + v.w;
            qq += v.x * v.x + v.y * v.y + v.z * v.z + v.w * v.w;
            _Float16 h0 = (_Float16)v.x, h1 = (_Float16)v.y,
                     h2 = (_Float16)v.z, h3 = (_Float16)v.w;
            _Float16 l0 = (_Float16)((v.x - (float)h0) * 2048.f);
            _Float16 l1 = (_Float16)((v.y - (float)h1) * 2048.f);
            _Float16 l2 = (_Float16)((v.z - (float)h2) * 2048.f);
            _Float16 l3 = (_Float16)((v.w - (float)h3) * 2048.f);
            half4h hh = {h0, h1, h2, h3};
            half4h ll = {l0, l1, l2, l3};
            int k0 = (cS + j * 32) * 4;
            *(half4h*)&Xh[rS][k0] = hh;
            *(half4h*)&Xl[rS][k0] = ll;
        }
        // row stats: 32 threads per row; lanes 0-31 = row 2wv', 32-63 = row 2wv'+1
        #pragma unroll
        for (int d = 1; d < 32; d <<= 1) {
            s  += __shfl_xor(s, d);
            qq += __shfl_xor(qq, d);
        }
        if ((lane & 31) == 0) {
            int r = rS;                      // lane 0 and 32 carry their own rows
            float mu  = s * (1.f / H);
            float var = qq * (1.f / H) - mu * mu;
            mu_s[r] = mu;
            rs_s[r] = rsqrtf(var + 1e-5f);
        }
        __syncthreads();                     // staging + stats visible

        // ---- issue next tile's X loads (in flight across entire phase B) ----
        if (tile + 1 < tiles) {
            const float4* src = X4 + (rowBase + MROWS + rS) * 512;
            #pragma unroll
            for (int j = 0; j < 16; ++j) vbuf[j] = src[cS + j * 32];
        }

        // ---- phase B: MFMA over this wave's K half, expert tile et ----
        f32x4 acc0 = (f32x4)0.f, acc1 = (f32x4)0.f, acc2 = (f32x4)0.f;
        {
            const int ks0 = kh * 32;
            int bo = ((ks0 * 4 + et) * 64 + lane) * 8;
            half8 Wh0 = *(const half8*)&Bh[bo];
            half8 Wl0 = *(const half8*)&Bl[bo];
            #pragma unroll 8
            for (int i = 0; i < 32; ++i) {
                int ks = ks0 + i;
                half8 Wh1, Wl1;
                if (i + 1 < 32) {
                    int bn = ((ks + 1) * 4 * 64 + et * 64 + lane) * 8;
                    Wh1 = *(const half8*)&Bh[bn];
                    Wl1 = *(const half8*)&Bl[bn];
                }
                half8 Ah = *(const half8*)&Xh[ln16][ks * 32 + q * 8];
                half8 Al = *(const half8*)&Xl[ln16][ks * 32 + q * 8];
                acc0 = MFMA16(Ah, Wh0, acc0);
                acc1 = MFMA16(Ah, Wl0, acc1);
                acc2 = MFMA16(Al, Wl0, acc2);
                acc1 = MFMA16(Al, Wh0, acc1);
                Wh0 = Wh1; Wl0 = Wl1;
            }
        }
        // combine splits into raw logit contribution (linear)
        float raw[4];
        #pragma unroll
        for (int reg = 0; reg < 4; ++reg)
            raw[reg] = acc0[reg] + acc1[reg] * (1.f / 2048.f)
                                 + acc2[reg] * (1.f / 4194304.f);
        __syncthreads();                     // phase B LDS reads done

        // ---- K-split reduce: waves 4-7 publish, waves 0-3 combine + epilogue ----
        if (kh == 1) {
            #pragma unroll
            for (int reg = 0; reg < 4; ++reg)
                redC[et][lane][reg] = raw[reg];
        }
        __syncthreads();
        if (kh == 0) {
            int n = et * 16 + ln16;
            float cs = csum[n], bs = bsum[n];
            #pragma unroll
            for (int reg = 0; reg < 4; ++reg) {
                int m = q * 4 + reg;
                float rt = raw[reg] + redC[et][lane][reg];
                float lg = rs_s[m] * (rt - mu_s[m] * cs) + bs;
                lg = fminf(fmaxf(lg, -10.f), 10.f);
                out[lOff + (rowBase + m) * 64 + n] = lg;
                C2[m][n] = lg;
            }
        }
        __syncthreads();                     // C2 complete

        // ---- softmax + top2: wave wv handles rows 2wv, 2wv+1 ----
        #pragma unroll
        for (int rr = 0; rr < 2; ++rr) {
            int r = wv * 2 + rr;
            float l = C2[r][lane];
            float m = l;
            #pragma unroll
            for (int d = 1; d < 64; d <<= 1) m = fmaxf(m, __shfl_xor(m, d));
            float p = __expf(l - m);
            float ssum = p;
            #pragma unroll
            for (int d = 1; d < 64; d <<= 1) ssum += __shfl_xor(ssum, d);
            float prob = fminf(fmaxf(p / ssum, 1e-4f), 1.0f);

            float v1 = prob; int i1 = lane;
            #pragma unroll
            for (int d = 1; d < 64; d <<= 1) {
                float ov = __shfl_xor(v1, d);
                int   oi = __shfl_xor(i1, d);
                if (ov > v1 || (ov == v1 && oi < i1)) { v1 = ov; i1 = oi; }
            }
            float v2 = (lane == i1) ? -1.f : prob; int i2 = lane;
            #pragma unroll
            for (int d = 1; d < 64; d <<= 1) {
                float ov = __shfl_xor(v2, d);
                int   oi = __shfl_xor(i2, d);
                if (ov > v2 || (ov == v2 && oi < i2)) { v2 = ov; i2 = oi; }
            }
            if (lane == 0) {
                float ps = fmaxf(v1 + v2, 1e-4f);
                long rg_ = rowBase + r;
                out[rg_ * 2 + 0] = v1 / ps;
                out[rg_ * 2 + 1] = v2 / ps;
                out[iOff + rg_ * 2 + 0] = (float)i1;
                out[iOff + rg_ * 2 + 1] = (float)i2;
            }
        }
        // next iteration's convert overwrites Xh/Xl (last read before barrier
        // after phase B) and mu_s (last read in epilogue) — both safe.
    }
}

extern "C" void kernel_launch(void* const* d_in, const int* in_sizes, int n_in,
                              void* d_out, int out_size, void* d_ws, size_t ws_size,
                              hipStream_t stream) {
    const float* X   = (const float*)d_in[0];
    const float* lnw = (const float*)d_in[1];
    const float* lnb = (const float*)d_in[2];
    const float* W   = (const float*)d_in[3];
    float* outp = (float*)d_out;

    _Float16* Bh = (_Float16*)d_ws;
    _Float16* Bl = Bh + H * E;
    float* csum  = (float*)(Bl + H * E);
    float* bsum  = csum + E;

    int N = in_sizes[0] / H;                 // 16384 rows

    prep_pack<<<(H * E / 8) / 256, 256, 0, stream>>>(W, lnw, Bh, Bl);
    prep_sums<<<E, 256, 0, stream>>>(W, lnw, lnb, csum, bsum);
    router_kernel<<<NBLK, 512, 0, stream>>>(X, Bh, Bl, csum, bsum, outp, N);
}

// Round 7
// 217.710 us; speedup vs baseline: 1.2807x; 1.1078x over previous
//
#include <hip/hip_runtime.h>
#include <math.h>

#define H 2048
#define E 64
#define MR 32        // rows per block
#define KCH 128      // k per chunk
#define NCH 16       // chunks
#define LR 136       // LDS row stride in f16 (128 + 8 pad; 272 B rows, 16B-aligned)

typedef _Float16 half8  __attribute__((ext_vector_type(8)));
typedef _Float16 half4h __attribute__((ext_vector_type(4)));
typedef float    f32x4  __attribute__((ext_vector_type(4)));

#define MFMA16(A,B,C) __builtin_amdgcn_mfma_f32_16x16x32_f16(A,B,C,0,0,0)

// ws layout: Bh[H*E f16] | Bl[H*E f16] | csum[E f32] | bsum[E f32]

// Pack W' = lnw*W into MFMA B-fragment layout, f16 hi/lo split (lo scaled by 2048).
// Fragment (ks, et): lane l holds B[k = ks*32 + (l>>4)*8 + j][n = et*16 + (l&15)], j=0..7.
__global__ __launch_bounds__(256) void prep_pack(const float* __restrict__ W,
        const float* __restrict__ lnw, _Float16* __restrict__ Bh,
        _Float16* __restrict__ Bl) {
    int idx  = blockIdx.x * 256 + threadIdx.x;      // 0..16383
    int lane = idx & 63;
    int ks   = idx >> 8;                            // 0..63
    int e  = ((idx >> 6) & 3) * 16 + (lane & 15);
    int k0 = ks * 32 + ((lane >> 4) << 3);
    half8 hh, ll;
    #pragma unroll
    for (int j = 0; j < 8; ++j) {
        float wf = lnw[k0 + j] * W[e * H + k0 + j];
        _Float16 h = (_Float16)wf;
        _Float16 l = (_Float16)((wf - (float)h) * 2048.0f);
        hh[j] = h; ll[j] = l;
    }
    *(half8*)&Bh[(long)idx * 8] = hh;
    *(half8*)&Bl[(long)idx * 8] = ll;
}

__global__ __launch_bounds__(256) void prep_sums(const float* __restrict__ W,
        const float* __restrict__ lnw, const float* __restrict__ lnb,
        float* __restrict__ csum, float* __restrict__ bsum) {
    __shared__ float rc[256], rb[256];
    int e = blockIdx.x, t = threadIdx.x;
    float cs = 0.f, bs = 0.f;
    #pragma unroll
    for (int j = 0; j < 8; ++j) {
        int k = t + j * 256;
        float w = W[e * H + k];
        cs += lnw[k] * w;
        bs += lnb[k] * w;
    }
    rc[t] = cs; rb[t] = bs;
    __syncthreads();
    for (int s = 128; s > 0; s >>= 1) {
        if (t < s) { rc[t] += rc[t + s]; rb[t] += rb[t + s]; }
        __syncthreads();
    }
    if (t == 0) { csum[e] = rc[0]; bsum[e] = rb[0]; }
}

__global__ __launch_bounds__(256) void router_kernel(
    const float* __restrict__ X, const _Float16* __restrict__ Bh,
    const _Float16* __restrict__ Bl, const float* __restrict__ csum,
    const float* __restrict__ bsum, float* __restrict__ out, int nRows)
{
    __shared__ __align__(16) _Float16 Xh[2][MR][LR];   // 17,408 B
    __shared__ __align__(16) _Float16 Xl[2][MR][LR];   // 17,408 B
    __shared__ float C2[MR][E + 4];                    //  8,704 B
    __shared__ float mu_s[MR], rs_s[MR];
    // total ~43.8 KB -> 3-block/CU capacity; grid 512 = 2 resident blocks/CU

    const int t    = threadIdx.x;
    const int lane = t & 63;
    const int et   = t >> 6;                 // wave -> expert tile (16 experts)
    const int q    = lane >> 4;
    const int ln16 = lane & 15;
    const int rowR = t >> 3;                 // this thread's staging/stats row 0..31
    const int cS   = t & 7;                  // float4 col group within chunk
    const long rowBase = (long)blockIdx.x * MR;
    const long iOff = (long)nRows * 2;
    const long lOff = (long)nRows * 4;

    const float4* X4 = (const float4*)X;
    const float4* Xrow = X4 + (rowBase + rowR) * 512;

    float sacc = 0.f, qacc = 0.f;            // LN stats, fixed row per thread

    // convert helper writes vb -> buf
    auto convert = [&](const float4* vb, int buf) {
        #pragma unroll
        for (int j = 0; j < 4; ++j) {
            float4 v = vb[j];
            sacc += v.x + v.y + v.z + v.w;
            qacc += v.x * v.x + v.y * v.y + v.z * v.z + v.w * v.w;
            _Float16 h0 = (_Float16)v.x, h1 = (_Float16)v.y,
                     h2 = (_Float16)v.z, h3 = (_Float16)v.w;
            _Float16 l0 = (_Float16)((v.x - (float)h0) * 2048.f);
            _Float16 l1 = (_Float16)((v.y - (float)h1) * 2048.f);
            _Float16 l2 = (_Float16)((v.z - (float)h2) * 2048.f);
            _Float16 l3 = (_Float16)((v.w - (float)h3) * 2048.f);
            half4h hh = {h0, h1, h2, h3};
            half4h ll = {l0, l1, l2, l3};
            int col = (cS + j * 8) * 4;
            *(half4h*)&Xh[buf][rowR][col] = hh;
            *(half4h*)&Xl[buf][rowR][col] = ll;
        }
    };

    // prologue: chunk 0 load + convert
    {
        float4 vb[4];
        #pragma unroll
        for (int j = 0; j < 4; ++j) vb[j] = Xrow[cS + j * 8];
        convert(vb, 0);
    }
    __syncthreads();

    f32x4 acc0[2] = {(f32x4)0.f, (f32x4)0.f};
    f32x4 acc1[2] = {(f32x4)0.f, (f32x4)0.f};

    for (int c = 0; c < NCH; ++c) {
        const int buf = c & 1;

        // ---- W burst for chunk c (oldest in vmcnt FIFO) ----
        half8 Wh[4], Wl[4];
        #pragma unroll
        for (int ks = 0; ks < 4; ++ks) {
            int bo = (((c * 4 + ks) * 4 + et) * 64 + lane) * 8;
            Wh[ks] = *(const half8*)&Bh[bo];
            Wl[ks] = *(const half8*)&Bl[bo];
        }
        // ---- X burst for chunk c+1 (newer -> W-uses don't wait on it) ----
        float4 vb[4];
        if (c + 1 < NCH) {
            #pragma unroll
            for (int j = 0; j < 4; ++j)
                vb[j] = Xrow[(c + 1) * 32 + cS + j * 8];
        }

        // ---- MFMA over chunk c ----
        #pragma unroll
        for (int ks = 0; ks < 4; ++ks) {
            #pragma unroll
            for (int m = 0; m < 2; ++m) {
                half8 Ah = *(const half8*)&Xh[buf][m * 16 + ln16][ks * 32 + q * 8];
                half8 Al = *(const half8*)&Xl[buf][m * 16 + ln16][ks * 32 + q * 8];
                acc0[m] = MFMA16(Ah, Wh[ks], acc0[m]);
                acc1[m] = MFMA16(Ah, Wl[ks], acc1[m]);
                acc1[m] = MFMA16(Al, Wh[ks], acc1[m]);
            }
        }

        // ---- convert chunk c+1 into other buffer (WAR-safe: barrier below) ----
        if (c + 1 < NCH) convert(vb, buf ^ 1);
        __syncthreads();
    }

    // ---- finalize LN stats (8 lanes per row: bits 0-2 of lane) ----
    {
        float s = sacc, qq = qacc;
        #pragma unroll
        for (int d = 1; d < 8; d <<= 1) {
            s  += __shfl_xor(s, d);
            qq += __shfl_xor(qq, d);
        }
        if ((lane & 7) == 0) {
            float mu  = s * (1.f / H);
            float var = qq * (1.f / H) - mu * mu;
            mu_s[rowR] = mu;
            rs_s[rowR] = rsqrtf(var + 1e-5f);
        }
    }
    __syncthreads();

    // ---- epilogue: combine splits, LN rank-1 correction, clip, write logits ----
    {
        int n = et * 16 + ln16;
        float cs = csum[n], bs = bsum[n];
        #pragma unroll
        for (int m = 0; m < 2; ++m) {
            #pragma unroll
            for (int reg = 0; reg < 4; ++reg) {
                int r = m * 16 + q * 4 + reg;
                float raw = acc0[m][reg] + acc1[m][reg] * (1.f / 2048.f);
                float lg = rs_s[r] * (raw - mu_s[r] * cs) + bs;
                lg = fminf(fmaxf(lg, -10.f), 10.f);
                out[lOff + (rowBase + r) * 64 + n] = lg;
                C2[r][n] = lg;
            }
        }
    }
    __syncthreads();

    // ---- softmax + top2: wave et handles rows et*8 .. et*8+7 ----
    #pragma unroll
    for (int rr = 0; rr < 8; ++rr) {
        int r = et * 8 + rr;
        float l = C2[r][lane];
        float m = l;
        #pragma unroll
        for (int d = 1; d < 64; d <<= 1) m = fmaxf(m, __shfl_xor(m, d));
        float p = __expf(l - m);
        float ssum = p;
        #pragma unroll
        for (int d = 1; d < 64; d <<= 1) ssum += __shfl_xor(ssum, d);
        float prob = fminf(fmaxf(p / ssum, 1e-4f), 1.0f);

        float v1 = prob; int i1 = lane;
        #pragma unroll
        for (int d = 1; d < 64; d <<= 1) {
            float ov = __shfl_xor(v1, d);
            int   oi = __shfl_xor(i1, d);
            if (ov > v1 || (ov == v1 && oi < i1)) { v1 = ov; i1 = oi; }
        }
        float v2 = (lane == i1) ? -1.f : prob; int i2 = lane;
        #pragma unroll
        for (int d = 1; d < 64; d <<= 1) {
            float ov = __shfl_xor(v2, d);
            int   oi = __shfl_xor(i2, d);
            if (ov > v2 || (ov == v2 && oi < i2)) { v2 = ov; i2 = oi; }
        }
        if (lane == 0) {
            float ps = fmaxf(v1 + v2, 1e-4f);
            long rg_ = rowBase + r;
            out[rg_ * 2 + 0] = v1 / ps;
            out[rg_ * 2 + 1] = v2 / ps;
            out[iOff + rg_ * 2 + 0] = (float)i1;
            out[iOff + rg_ * 2 + 1] = (float)i2;
        }
    }
}

extern "C" void kernel_launch(void* const* d_in, const int* in_sizes, int n_in,
                              void* d_out, int out_size, void* d_ws, size_t ws_size,
                              hipStream_t stream) {
    const float* X   = (const float*)d_in[0];
    const float* lnw = (const float*)d_in[1];
    const float* lnb = (const float*)d_in[2];
    const float* W   = (const float*)d_in[3];
    float* outp = (float*)d_out;

    _Float16* Bh = (_Float16*)d_ws;
    _Float16* Bl = Bh + H * E;
    float* csum  = (float*)(Bl + H * E);
    float* bsum  = csum + E;

    int N = in_sizes[0] / H;                 // 16384 rows

    prep_pack<<<(H * E / 8) / 256, 256, 0, stream>>>(W, lnw, Bh, Bl);
    prep_sums<<<E, 256, 0, stream>>>(W, lnw, lnb, csum, bsum);
    router_kernel<<<N / MR, 256, 0, stream>>>(X, Bh, Bl, csum, bsum, outp, N);
}